// Round 14
// baseline (350.715 us; speedup 1.0000x reference)
//
#include <hip/hip_runtime.h>

// ---------------------------------------------------------------------------
// UMAALayer: 3-modality cross-attention + pairwise contrastive loss + FFN.
// M=3, B=4, N=2048, D=256, H=4, HD=64, DFF=1024, TEMP=0.07, EPS=1e-5.
// v8: k_attn staging via __builtin_amdgcn_global_load_lds (width=16, async
// DMA into the other buffer, published by the end-of-iter barrier drain).
// LDS is unpadded [64][64] with XOR swizzle: source col pre-swizzled
// (slot ^ row&7), reads apply the same XOR. Frees 16 staging VGPRs ->
// __launch_bounds__(256,4) for 4 waves/SIMD. Math identical to v7 (passed
// at 0.375): shift-free P, max-shifted loss l2run. No atomics.
// ---------------------------------------------------------------------------

typedef float f32x2 __attribute__((ext_vector_type(2)));
typedef float f32x4 __attribute__((ext_vector_type(4)));
typedef float f32x16 __attribute__((ext_vector_type(16)));
typedef __bf16 bf16x8 __attribute__((ext_vector_type(8)));
typedef unsigned int u32x2 __attribute__((ext_vector_type(2)));
typedef unsigned int u32x4 __attribute__((ext_vector_type(4)));
typedef unsigned short bfu4 __attribute__((ext_vector_type(4)));
typedef unsigned short bfu;

#define MFMA32(a, b, c) __builtin_amdgcn_mfma_f32_32x32x16_bf16(a, b, c, 0, 0, 0)

#define NTOK 2048
#define DIMM 256
#define HDIM 64
#define DFF 1024
#define OUT_LOSS 6291456    // 3*4*2048*256
#define INVT 14.285714285714286f   // 1/0.07
#define LN2F 0.6931471805599453f
#define LOG2EF 1.4426950408889634f

#define EXP2F(x) __builtin_amdgcn_exp2f(x)
#define LOG2F(x) __builtin_amdgcn_logf(x)   // v_log_f32 = log2(x)

__device__ __forceinline__ bfu f2bf(float f) {
  unsigned u = __float_as_uint(f);
  u += 0x7FFFu + ((u >> 16) & 1u);          // RNE
  return (bfu)(u >> 16);
}
__device__ __forceinline__ float frombf(bfu v) {
  return __uint_as_float(((unsigned)v) << 16);
}

__device__ __forceinline__ bf16x8 ldfrag(const bfu* p) {
  return __builtin_bit_cast(bf16x8, *reinterpret_cast<const u32x4*>(p));
}

// async global->LDS DMA, 16B/lane; LDS dest is wave-uniform base + lane*16.
__device__ __forceinline__ void gl16(const bfu* g, bfu* l) {
  __builtin_amdgcn_global_load_lds(
      (const __attribute__((address_space(1))) unsigned int*)g,
      (__attribute__((address_space(3))) unsigned int*)l, 16, 0, 0);
}

// v_cvt_pk_bf16_f32: D[15:0]=bf16(lo), D[31:16]=bf16(hi)
__device__ __forceinline__ unsigned pkbf(float lo, float hi) {
  unsigned d;
  asm("v_cvt_pk_bf16_f32 %0, %1, %2" : "=v"(d) : "v"(lo), "v"(hi));
  return d;
}
__device__ __forceinline__ void swap32u(unsigned& a, unsigned& b) {
  asm("v_permlane32_swap_b32 %0, %1" : "+v"(a), "+v"(b));
}
__device__ __forceinline__ float red32_add(float x) {
  float y = x;
  asm("v_permlane32_swap_b32 %0, %1" : "+v"(x), "+v"(y));
  return x + y;
}
__device__ __forceinline__ float red32_max(float x) {
  float y = x;
  asm("v_permlane32_swap_b32 %0, %1" : "+v"(x), "+v"(y));
  return fmaxf(x, y);
}

// ---------------- fused fp32 -> bf16 conversion (all 8 tensors) ------------
__global__ __launch_bounds__(256) void k_cvt_all(
    const float* __restrict__ m0, const float* __restrict__ m1,
    const float* __restrict__ m2, const float* __restrict__ Wq,
    const float* __restrict__ Wk, const float* __restrict__ Wv,
    const float* __restrict__ W1, const float* __restrict__ W2,
    bfu* __restrict__ Xb, bfu* __restrict__ Wqkv,
    bfu* __restrict__ W1b, bfu* __restrict__ W2b) {
  const int bid = blockIdx.x, tid = threadIdx.x;
  const float* src;
  bfu* dst;
  int idx;
  if (bid < 6144) {
    const int seg = bid >> 11;
    src = (seg == 0) ? m0 : (seg == 1 ? m1 : m2);
    dst = Xb + (size_t)seg * 2097152;
    idx = (bid & 2047) * 256 + tid;
  } else if (bid < 6336) {
    const int wseg = (bid - 6144) >> 6;
    src = (wseg == 0) ? Wq : (wseg == 1 ? Wk : Wv);
    dst = Wqkv + (size_t)wseg * 65536;
    idx = ((bid - 6144) & 63) * 256 + tid;
  } else if (bid < 6592) {
    src = W1; dst = W1b; idx = (bid - 6336) * 256 + tid;
  } else {
    src = W2; dst = W2b; idx = (bid - 6592) * 256 + tid;
  }
  f32x4 v = reinterpret_cast<const f32x4*>(src)[idx];
  bfu4 o;
  o[0] = f2bf(v[0]); o[1] = f2bf(v[1]); o[2] = f2bf(v[2]); o[3] = f2bf(v[3]);
  reinterpret_cast<bfu4*>(dst)[idx] = o;
}

// ======================= LDS-staged GEMM building blocks ====================
#define RROW(r) (((r) & 3) + 8 * ((r) >> 2) + 4 * hi)

// ---------------- k_proj: [24576,256] x [768,256]^T -> Q/K/VT ---------------
// grid (192, 6). Q pre-scaled by 0.125*log2e (log2-domain scores).
__global__ __launch_bounds__(256) void k_proj(const bfu* __restrict__ Xb,
                                              const bfu* __restrict__ Wcat,
                                              bfu* __restrict__ Qb,
                                              bfu* __restrict__ Kb,
                                              bfu* __restrict__ VTb) {
  __shared__ __align__(16) bfu sA[128][72];
  __shared__ __align__(16) bfu sB[128][72];
  const int tid = threadIdx.x;
  const int lane = tid & 63, w = tid >> 6;
  const int l31 = lane & 31, hi = lane >> 5, hi8 = hi * 8;
  const int wm = w >> 1, wn = w & 1;
  const int row0 = blockIdx.x * 128;
  const int col0 = blockIdx.y * 128;
  const bfu* Ap = Xb + (size_t)row0 * 256;
  const bfu* Bp = Wcat + (size_t)col0 * 256;
  f32x16 acc00 = {}, acc01 = {}, acc10 = {}, acc11 = {};
  u32x4 rA[4], rB[4];
#pragma unroll
  for (int t = 0; t < 4; ++t) {
    const int c = tid + 256 * t;
    rA[t] = *reinterpret_cast<const u32x4*>(Ap + (size_t)(c >> 3) * 256 + (c & 7) * 8);
    rB[t] = *reinterpret_cast<const u32x4*>(Bp + (size_t)(c >> 3) * 256 + (c & 7) * 8);
  }
#pragma unroll
  for (int ks = 0; ks < 4; ++ks) {
    __syncthreads();
#pragma unroll
    for (int t = 0; t < 4; ++t) {
      const int c = tid + 256 * t;
      *reinterpret_cast<u32x4*>(&sA[c >> 3][(c & 7) * 8]) = rA[t];
      *reinterpret_cast<u32x4*>(&sB[c >> 3][(c & 7) * 8]) = rB[t];
    }
    __syncthreads();
    if (ks < 3) {
      const int k0 = (ks + 1) * 64;
#pragma unroll
      for (int t = 0; t < 4; ++t) {
        const int c = tid + 256 * t;
        rA[t] = *reinterpret_cast<const u32x4*>(Ap + (size_t)(c >> 3) * 256 + k0 + (c & 7) * 8);
        rB[t] = *reinterpret_cast<const u32x4*>(Bp + (size_t)(c >> 3) * 256 + k0 + (c & 7) * 8);
      }
    }
#pragma unroll
    for (int kk = 0; kk < 4; ++kk) {
      bf16x8 a0 = ldfrag(&sA[wm * 64 + l31][kk * 16 + hi8]);
      bf16x8 a1 = ldfrag(&sA[wm * 64 + 32 + l31][kk * 16 + hi8]);
      bf16x8 b0 = ldfrag(&sB[wn * 64 + l31][kk * 16 + hi8]);
      bf16x8 b1 = ldfrag(&sB[wn * 64 + 32 + l31][kk * 16 + hi8]);
      acc00 = MFMA32(a0, b0, acc00);
      acc01 = MFMA32(a0, b1, acc01);
      acc10 = MFMA32(a1, b0, acc10);
      acc11 = MFMA32(a1, b1, acc11);
    }
  }
  const int mb = row0 >> 11;                    // (m*4+b), uniform per block
  const int cb = col0 + wn * 64;                // 64-aligned -> which,h uniform
  const int which = cb >> 8;
  const int h = (cb >> 6) & 3;
  const size_t obase = ((size_t)mb * 4 + h) * ((size_t)NTOK * HDIM);
  const int tokb = (row0 & 2047) + wm * 64;
  const float qs = (which == 0) ? 0.125f * LOG2EF : 1.0f;
#define STORE_QK(ACC, MT, NT)                                                 \
  {                                                                           \
    bfu* dst = (which ? Kb : Qb) + obase;                                     \
    _Pragma("unroll") for (int r = 0; r < 16; ++r) {                          \
      const int tok = tokb + (MT) * 32 + RROW(r);                             \
      dst[(size_t)tok * 64 + (NT) * 32 + l31] = f2bf((ACC)[r] * qs);          \
    }                                                                         \
  }
#define STORE_VT(ACC, MT, NT)                                                 \
  {                                                                           \
    _Pragma("unroll") for (int g = 0; g < 4; ++g) {                           \
      bfu4 pk;                                                                \
      _Pragma("unroll") for (int q = 0; q < 4; ++q) pk[q] = f2bf((ACC)[4 * g + q]); \
      const int tok = tokb + (MT) * 32 + 8 * g + 4 * hi;                      \
      *reinterpret_cast<bfu4*>(                                               \
          &VTb[obase + (size_t)((NT) * 32 + l31) * NTOK + tok]) = pk;         \
    }                                                                         \
  }
  if (which < 2) {
    STORE_QK(acc00, 0, 0) STORE_QK(acc01, 0, 1)
    STORE_QK(acc10, 1, 0) STORE_QK(acc11, 1, 1)
  } else {
    STORE_VT(acc00, 0, 0) STORE_VT(acc01, 0, 1)
    STORE_VT(acc10, 1, 0) STORE_VT(acc11, 1, 1)
  }
}

// ---------------- k_ffn1: h = gelu(x1b @ W1^T + bm1) ------------------------
__global__ __launch_bounds__(256) void k_ffn1(const bfu* __restrict__ x1b,
                                              const bfu* __restrict__ W1b,
                                              const float* __restrict__ bm1,
                                              bfu* __restrict__ hb) {
  __shared__ __align__(16) bfu sA[128][72];
  __shared__ __align__(16) bfu sB[128][72];
  const int tid = threadIdx.x;
  const int lane = tid & 63, w = tid >> 6;
  const int l31 = lane & 31, hi = lane >> 5, hi8 = hi * 8;
  const int wm = w >> 1, wn = w & 1;
  const int row0 = blockIdx.x * 128;
  const int col0 = blockIdx.y * 128;
  const bfu* Ap = x1b + (size_t)row0 * 256;
  const bfu* Bp = W1b + (size_t)col0 * 256;
  f32x16 acc00 = {}, acc01 = {}, acc10 = {}, acc11 = {};
  u32x4 rA[4], rB[4];
#pragma unroll
  for (int t = 0; t < 4; ++t) {
    const int c = tid + 256 * t;
    rA[t] = *reinterpret_cast<const u32x4*>(Ap + (size_t)(c >> 3) * 256 + (c & 7) * 8);
    rB[t] = *reinterpret_cast<const u32x4*>(Bp + (size_t)(c >> 3) * 256 + (c & 7) * 8);
  }
#pragma unroll
  for (int ks = 0; ks < 4; ++ks) {
    __syncthreads();
#pragma unroll
    for (int t = 0; t < 4; ++t) {
      const int c = tid + 256 * t;
      *reinterpret_cast<u32x4*>(&sA[c >> 3][(c & 7) * 8]) = rA[t];
      *reinterpret_cast<u32x4*>(&sB[c >> 3][(c & 7) * 8]) = rB[t];
    }
    __syncthreads();
    if (ks < 3) {
      const int k0 = (ks + 1) * 64;
#pragma unroll
      for (int t = 0; t < 4; ++t) {
        const int c = tid + 256 * t;
        rA[t] = *reinterpret_cast<const u32x4*>(Ap + (size_t)(c >> 3) * 256 + k0 + (c & 7) * 8);
        rB[t] = *reinterpret_cast<const u32x4*>(Bp + (size_t)(c >> 3) * 256 + k0 + (c & 7) * 8);
      }
    }
#pragma unroll
    for (int kk = 0; kk < 4; ++kk) {
      bf16x8 a0 = ldfrag(&sA[wm * 64 + l31][kk * 16 + hi8]);
      bf16x8 a1 = ldfrag(&sA[wm * 64 + 32 + l31][kk * 16 + hi8]);
      bf16x8 b0 = ldfrag(&sB[wn * 64 + l31][kk * 16 + hi8]);
      bf16x8 b1 = ldfrag(&sB[wn * 64 + 32 + l31][kk * 16 + hi8]);
      acc00 = MFMA32(a0, b0, acc00);
      acc01 = MFMA32(a0, b1, acc01);
      acc10 = MFMA32(a1, b0, acc10);
      acc11 = MFMA32(a1, b1, acc11);
    }
  }
  const int tokb = row0 + wm * 64;
#define STORE_H(ACC, MT, NT)                                                  \
  {                                                                           \
    const int e = col0 + wn * 64 + (NT) * 32 + l31;                           \
    const float bias = bm1[e];                                                \
    _Pragma("unroll") for (int r = 0; r < 16; ++r) {                          \
      const int tok = tokb + (MT) * 32 + RROW(r);                             \
      float v = (ACC)[r] + bias;                                              \
      v = 0.5f * v * (1.0f + erff(v * 0.70710678118f));                       \
      hb[(size_t)tok * DFF + e] = f2bf(v);                                    \
    }                                                                         \
  }
  STORE_H(acc00, 0, 0) STORE_H(acc01, 0, 1)
  STORE_H(acc10, 1, 0) STORE_H(acc11, 1, 1)
}

// ---------------- k_ffn2: y = hb @ W2^T + bm2 + x1 (pre-LN) -> x2f ----------
__global__ __launch_bounds__(256) void k_ffn2(const bfu* __restrict__ hb,
                                              const bfu* __restrict__ W2b,
                                              const float* __restrict__ bm2,
                                              const bfu* __restrict__ x1b,
                                              float* __restrict__ x2f) {
  __shared__ __align__(16) bfu sA[128][72];
  __shared__ __align__(16) bfu sB[64][72];
  const int tid = threadIdx.x;
  const int lane = tid & 63, w = tid >> 6;
  const int l31 = lane & 31, hi = lane >> 5, hi8 = hi * 8;
  const int row0 = blockIdx.x * 128;
  const int col0 = blockIdx.y * 64;
  const bfu* Ap = hb + (size_t)row0 * DFF;
  const bfu* Bp = W2b + (size_t)col0 * DFF;
  f32x16 acc0 = {}, acc1 = {};
  u32x4 rA[4], rB[2];
#pragma unroll
  for (int t = 0; t < 4; ++t) {
    const int c = tid + 256 * t;
    rA[t] = *reinterpret_cast<const u32x4*>(Ap + (size_t)(c >> 3) * DFF + (c & 7) * 8);
  }
#pragma unroll
  for (int t = 0; t < 2; ++t) {
    const int c = tid + 256 * t;
    rB[t] = *reinterpret_cast<const u32x4*>(Bp + (size_t)(c >> 3) * DFF + (c & 7) * 8);
  }
  for (int ks = 0; ks < 16; ++ks) {
    __syncthreads();
#pragma unroll
    for (int t = 0; t < 4; ++t) {
      const int c = tid + 256 * t;
      *reinterpret_cast<u32x4*>(&sA[c >> 3][(c & 7) * 8]) = rA[t];
    }
#pragma unroll
    for (int t = 0; t < 2; ++t) {
      const int c = tid + 256 * t;
      *reinterpret_cast<u32x4*>(&sB[c >> 3][(c & 7) * 8]) = rB[t];
    }
    __syncthreads();
    if (ks < 15) {
      const int k0 = (ks + 1) * 64;
#pragma unroll
      for (int t = 0; t < 4; ++t) {
        const int c = tid + 256 * t;
        rA[t] = *reinterpret_cast<const u32x4*>(Ap + (size_t)(c >> 3) * DFF + k0 + (c & 7) * 8);
      }
#pragma unroll
      for (int t = 0; t < 2; ++t) {
        const int c = tid + 256 * t;
        rB[t] = *reinterpret_cast<const u32x4*>(Bp + (size_t)(c >> 3) * DFF + k0 + (c & 7) * 8);
      }
    }
#pragma unroll
    for (int kk = 0; kk < 4; ++kk) {
      bf16x8 a = ldfrag(&sA[w * 32 + l31][kk * 16 + hi8]);
      bf16x8 b0 = ldfrag(&sB[l31][kk * 16 + hi8]);
      bf16x8 b1 = ldfrag(&sB[32 + l31][kk * 16 + hi8]);
      acc0 = MFMA32(a, b0, acc0);
      acc1 = MFMA32(a, b1, acc1);
    }
  }
  const int tokb = row0 + w * 32;
#define STORE_Y(ACC, NT)                                                      \
  {                                                                           \
    const int e = col0 + (NT) * 32 + l31;                                     \
    const float bias = bm2[e];                                                \
    _Pragma("unroll") for (int r = 0; r < 16; ++r) {                          \
      const int tok = tokb + RROW(r);                                         \
      x2f[(size_t)tok * DIMM + e] =                                           \
          (ACC)[r] + bias + frombf(x1b[(size_t)tok * DIMM + e]);              \
    }                                                                         \
  }
  STORE_Y(acc0, 0) STORE_Y(acc1, 1)
}

// ---------------- fused cross-attention + contrastive-loss v8 --------------
// grid (16 qt, 16 bh, 9 ij). 4 waves x 32 q-rows; double-buffer LDS with
// global_load_lds async staging (one barrier/iter); XOR-swizzled [64][64]
// tiles (source pre-swizzle + read swizzle). Math identical to v7.
__global__ __launch_bounds__(256, 4) void k_attn(const bfu* __restrict__ Qb,
                                                 const bfu* __restrict__ Kb,
                                                 const bfu* __restrict__ VTb,
                                                 bfu* __restrict__ upd3,
                                                 float* __restrict__ lossbuf) {
  __shared__ __align__(16) bfu sK[2][64][64];
  __shared__ __align__(16) bfu sV[2][64][64];
  __shared__ float sRed[4];
  const int tid = threadIdx.x;
  const int lane = tid & 63, w = tid >> 6;
  const int l31 = lane & 31, hi = lane >> 5;
  const int hi8 = hi * 8;
  const int qt = blockIdx.x, bh = blockIdx.y, ij = blockIdx.z;
  const int i = ij / 3, j = ij % 3;
  const bool wl = (i != j);
  const int b = bh >> 2, h = bh & 3;
  const int q0 = qt * 128 + w * 32;
  const int q = q0 + l31;
  const int ktd = q0 >> 6;                 // kt index containing the diagonal
  const size_t plane = (size_t)NTOK * HDIM;
  const size_t qoff = (((size_t)i * 4 + b) * 4 + h) * plane;
  const size_t kvoff = (((size_t)j * 4 + b) * 4 + h) * plane;
  const bfu* Kp = Kb + kvoff;
  const bfu* Vp = VTb + kvoff;

  // staging geometry: one gl16 call fills 8 rows (64 lanes x 16B = 1KB).
  // lane covers dest row r0_=(w*16 + lane>>3), 16B-slot (lane&7); the source
  // col is pre-swizzled so that LDS slot s of row r holds src col (s^(r&7))*8.
  const int r0_ = w * 16 + (lane >> 3);
  const int c0_ = ((lane & 7) ^ (r0_ & 7)) * 8;   // same for row r0_+8
  const bfu* KpS0 = Kp + (size_t)r0_ * HDIM + c0_;
  const bfu* KpS1 = Kp + (size_t)(r0_ + 8) * HDIM + c0_;
  const bfu* VpS0 = Vp + (size_t)r0_ * NTOK + c0_;
  const bfu* VpS1 = Vp + (size_t)(r0_ + 8) * NTOK + c0_;

  bf16x8 qf[4];
#pragma unroll
  for (int c = 0; c < 4; ++c)
    qf[c] = ldfrag(Qb + qoff + (size_t)q * HDIM + c * 16 + hi8);

  float lossacc = 0.0f;
  float mrun = -1e30f, lrun = 0.0f, l2run = 0.0f;
  f32x16 O0 = {}, O1 = {};
  const int sw = (l31 & 7) * 8;             // read-side swizzle XOR (elements)

#define STAGE(K0, BUF)                                                       \
    {                                                                        \
      gl16(KpS0 + (size_t)(K0) * HDIM, &sK[BUF][w * 16][0]);                 \
      gl16(KpS1 + (size_t)(K0) * HDIM, &sK[BUF][w * 16 + 8][0]);             \
      gl16(VpS0 + (K0), &sV[BUF][w * 16][0]);                                \
      gl16(VpS1 + (K0), &sV[BUF][w * 16 + 8][0]);                            \
    }

  STAGE(0, 0);
  __syncthreads();                          // drains vmcnt before barrier
  int cur = 0;

  for (int kt = 0; kt < 32; ++kt) {
    if (kt < 31) STAGE((kt + 1) * 64, cur ^ 1);   // async DMA, overlaps compute

    // ---- S^T = K_tile x Q  (64k x 32q per wave), log2-domain ----
    f32x16 S0 = {}, S1 = {};
    __builtin_amdgcn_s_setprio(1);
#pragma unroll
    for (int c = 0; c < 4; ++c) {
      bf16x8 a0 = ldfrag(&sK[cur][l31][(c * 16 + hi8) ^ sw]);
      bf16x8 a1 = ldfrag(&sK[cur][32 + l31][(c * 16 + hi8) ^ sw]);
      S0 = MFMA32(a0, qf[c], S0);
      S1 = MFMA32(a1, qf[c], S1);
    }
    __builtin_amdgcn_s_setprio(0);

    if (wl) {
      // ---- loss diagonal: sim = S * ln2 ----
      if (kt == ktd) {
#pragma unroll
        for (int r = 0; r < 16; ++r) {
          const int klow = (r & 3) + 8 * (r >> 2) + 4 * hi;
          const float sv = (w & 1) ? S1[r] : S0[r];
          if (klow == l31) lossacc -= sv * LN2F;
        }
      }
      // ---- loss max tracking (defer, THR=1.9) — only l2run is shifted ----
      float pmax = -1e30f;
#pragma unroll
      for (int r = 0; r < 16; ++r) pmax = fmaxf(pmax, fmaxf(S0[r], S1[r]));
      pmax = red32_max(pmax);
      if (__any(pmax > mrun + 1.9f)) {
        const float mnew = fmaxf(mrun, pmax);
        l2run *= EXP2F((mrun - mnew) * INVT);
        mrun = mnew;
      }
    }

    // ---- softmax exps (shift-free) + loss exps (max-shifted) ----
    const float mI = mrun * INVT;
    f32x2 psv = {};
    f32x2 p2v = {};
#pragma unroll
    for (int r = 0; r < 16; ++r) {
      const float e0 = EXP2F(S0[r]), e1 = EXP2F(S1[r]);
      f32x2 ev; ev[0] = e0; ev[1] = e1;
      psv += ev;
      if (wl) {
        f32x2 pv2;
        pv2[0] = EXP2F(fmaf(S0[r], INVT, -mI));
        pv2[1] = EXP2F(fmaf(S1[r], INVT, -mI));
        p2v += pv2;
      }
      S0[r] = e0; S1[r] = e1;
    }
    lrun += red32_add(psv[0] + psv[1]);
    if (wl) l2run += red32_add(p2v[0] + p2v[1]);

    // ---- per-chunk: build P^T B-fragment in-register, then its PV MFMAs ----
    __builtin_amdgcn_s_setprio(1);
#pragma unroll
    for (int c = 0; c < 4; ++c) {
      const int half = c >> 1, sub = c & 1;
      unsigned q01, q23, q45, q67;
      if (half == 0) {
        q01 = pkbf(S0[sub * 8 + 0], S0[sub * 8 + 1]);
        q23 = pkbf(S0[sub * 8 + 2], S0[sub * 8 + 3]);
        q45 = pkbf(S0[sub * 8 + 4], S0[sub * 8 + 5]);
        q67 = pkbf(S0[sub * 8 + 6], S0[sub * 8 + 7]);
      } else {
        q01 = pkbf(S1[sub * 8 + 0], S1[sub * 8 + 1]);
        q23 = pkbf(S1[sub * 8 + 2], S1[sub * 8 + 3]);
        q45 = pkbf(S1[sub * 8 + 4], S1[sub * 8 + 5]);
        q67 = pkbf(S1[sub * 8 + 6], S1[sub * 8 + 7]);
      }
      swap32u(q01, q45);
      swap32u(q23, q67);
      u32x4 bb; bb[0] = q01; bb[1] = q23; bb[2] = q45; bb[3] = q67;
      const bf16x8 pb = __builtin_bit_cast(bf16x8, bb);
      bf16x8 a0 = ldfrag(&sV[cur][l31][(c * 16 + hi8) ^ sw]);
      bf16x8 a1 = ldfrag(&sV[cur][32 + l31][(c * 16 + hi8) ^ sw]);
      O0 = MFMA32(a0, pb, O0);
      O1 = MFMA32(a1, pb, O1);
    }
    __builtin_amdgcn_s_setprio(0);

    // one barrier per iter: drains the DMA (vmcnt) + retires buf[cur] reads.
    __syncthreads();
    cur ^= 1;
  }  // kt

  // ---- store O/l (bf16) to this block's exclusive upd3 slice ----
  const float inv = 1.0f / lrun;
  bfu* up = upd3 + ((size_t)((j * 3 + i) * 4 + b) * NTOK + q) * DIMM + h * 64;
#pragma unroll
  for (int g = 0; g < 4; ++g) {
    u32x2 st0, st1;
    st0[0] = pkbf(O0[4 * g + 0] * inv, O0[4 * g + 1] * inv);
    st0[1] = pkbf(O0[4 * g + 2] * inv, O0[4 * g + 3] * inv);
    st1[0] = pkbf(O1[4 * g + 0] * inv, O1[4 * g + 1] * inv);
    st1[1] = pkbf(O1[4 * g + 2] * inv, O1[4 * g + 3] * inv);
    *reinterpret_cast<u32x2*>(up + 8 * g + 4 * hi) = st0;
    *reinterpret_cast<u32x2*>(up + 32 + 8 * g + 4 * hi) = st1;
  }
  // lse contribution: ln2 * (m*INVT + log2(l2run))
  if (wl && hi == 0)
    lossacc += LN2F * (mrun * INVT + LOG2F(l2run));

  float v = lossacc;
#pragma unroll
  for (int mk = 1; mk < 64; mk <<= 1) v += __shfl_xor(v, mk);
  if (lane == 0) sRed[w] = v;
  __syncthreads();
  if (tid == 0)
    lossbuf[((size_t)ij * 16 + bh) * 16 + qt] =
        sRed[0] + sRed[1] + sRed[2] + sRed[3];
}

// ---------------- residual + LayerNorm1 (1 row / wave) ---------------------
__global__ __launch_bounds__(256) void k_ln1(const float* __restrict__ m0,
                                             const float* __restrict__ m1,
                                             const float* __restrict__ m2,
                                             const bfu* __restrict__ upd3,
                                             const float* __restrict__ g1,
                                             const float* __restrict__ be1,
                                             bfu* __restrict__ x1b) {
  const int tid = threadIdx.x;
  const int lane = tid & 63, w = tid >> 6;
  const int row = blockIdx.x * 4 + w;
  const int i = row >> 13;
  const int rr = row & 8191;
  const float* src = (i == 0 ? m0 : (i == 1 ? m1 : m2)) + (size_t)rr * DIMM;
  f32x4 x = *reinterpret_cast<const f32x4*>(src + lane * 4);
#pragma unroll
  for (int j = 0; j < 3; ++j) {
    bfu4 uv = *reinterpret_cast<const bfu4*>(
        upd3 + ((size_t)(j * 3 + i) * 8192 + rr) * DIMM + lane * 4);
#pragma unroll
    for (int qi = 0; qi < 4; ++qi) x[qi] += frombf(uv[qi]);
  }
  float s = x[0] + x[1] + x[2] + x[3];
  float s2 = x[0] * x[0] + x[1] * x[1] + x[2] * x[2] + x[3] * x[3];
#pragma unroll
  for (int mk = 1; mk < 64; mk <<= 1) { s += __shfl_xor(s, mk); s2 += __shfl_xor(s2, mk); }
  const float mu = s * (1.0f / 256.0f);
  const float var = s2 * (1.0f / 256.0f) - mu * mu;
  const float rstd = rsqrtf(var + 1e-5f);
  f32x4 g = *reinterpret_cast<const f32x4*>(g1 + lane * 4);
  f32x4 bb = *reinterpret_cast<const f32x4*>(be1 + lane * 4);
  bfu4 ob;
#pragma unroll
  for (int qi = 0; qi < 4; ++qi)
    ob[qi] = f2bf((x[qi] - mu) * rstd * g[qi] + bb[qi]);
  *reinterpret_cast<bfu4*>(x1b + (size_t)row * DIMM + lane * 4) = ob;
}

// ---------------- LayerNorm2: x2f -> out ------------------------------------
__global__ __launch_bounds__(256) void k_ln2(const float* __restrict__ x2f,
                                             const float* __restrict__ g2,
                                             const float* __restrict__ be2,
                                             float* __restrict__ out) {
  const int tid = threadIdx.x;
  const int lane = tid & 63, w = tid >> 6;
  const int row = blockIdx.x * 4 + w;
  f32x4 x = *reinterpret_cast<const f32x4*>(x2f + (size_t)row * DIMM + lane * 4);
  float s = x[0] + x[1] + x[2] + x[3];
  float s2 = x[0] * x[0] + x[1] * x[1] + x[2] * x[2] + x[3] * x[3];
#pragma unroll
  for (int mk = 1; mk < 64; mk <<= 1) { s += __shfl_xor(s, mk); s2 += __shfl_xor(s2, mk); }
  const float mu = s * (1.0f / 256.0f);
  const float var = s2 * (1.0f / 256.0f) - mu * mu;
  const float rstd = rsqrtf(var + 1e-5f);
  f32x4 g = *reinterpret_cast<const f32x4*>(g2 + lane * 4);
  f32x4 bb = *reinterpret_cast<const f32x4*>(be2 + lane * 4);
  f32x4 o;
#pragma unroll
  for (int qi = 0; qi < 4; ++qi) o[qi] = (x[qi] - mu) * rstd * g[qi] + bb[qi];
  *reinterpret_cast<f32x4*>(out + (size_t)row * DIMM + lane * 4) = o;
}

// ---------------- final loss reduce (deterministic) -------------------------
__global__ __launch_bounds__(256) void k_loss(const float* __restrict__ lossbuf,
                                              float* __restrict__ out) {
  __shared__ float red[4];
  const int tid = threadIdx.x;
  float s = 0.0f;
  for (int idx = tid; idx < 2304; idx += 256) s += lossbuf[idx];
#pragma unroll
  for (int mk = 1; mk < 64; mk <<= 1) s += __shfl_xor(s, mk);
  if ((tid & 63) == 0) red[tid >> 6] = s;
  __syncthreads();
  if (tid == 0)
    out[OUT_LOSS] = (red[0] + red[1] + red[2] + red[3]) * (1.0f / (32768.0f * 2.0f));
}

// ---------------------------------------------------------------------------
extern "C" void kernel_launch(void* const* d_in, const int* in_sizes, int n_in,
                              void* d_out, int out_size, void* d_ws, size_t ws_size,
                              hipStream_t stream) {
  const float* m0 = (const float*)d_in[0];
  const float* m1 = (const float*)d_in[1];
  const float* m2 = (const float*)d_in[2];
  const float* Wq = (const float*)d_in[3];
  const float* Wk = (const float*)d_in[4];
  const float* Wv = (const float*)d_in[5];
  const float* g1 = (const float*)d_in[6];
  const float* be1 = (const float*)d_in[7];
  const float* W1 = (const float*)d_in[8];
  const float* bm1 = (const float*)d_in[9];
  const float* W2 = (const float*)d_in[10];
  const float* bm2 = (const float*)d_in[11];
  const float* g2 = (const float*)d_in[12];
  const float* be2 = (const float*)d_in[13];
  float* out = (float*)d_out;

  // workspace layout (bytes), peak ~102.2 MB (same as v7)
  char* ws = (char*)d_ws;
  bfu* Xb   = (bfu*)(ws + 0);            // 12,582,912
  bfu* Wqkv = (bfu*)(ws + 12582912);     //    393,216
  bfu* Qb   = (bfu*)(ws + 12976128);     // 12,582,912
  bfu* Kb   = (bfu*)(ws + 25559040);     // 12,582,912
  bfu* VTb  = (bfu*)(ws + 38141952);     // 12,582,912
  bfu* Hb   = (bfu*)(ws + 0);            // 50,331,648 [overlay]
  bfu* upd3 = (bfu*)(ws + 50724864);     // 37,748,736 (3 slices bf16)
  float* x2f = (float*)(ws + 50724864);  // 25,165,824 [overlays upd3 after ln1]
  bfu* x1b  = (bfu*)(ws + 88473600);     // 12,582,912
  bfu* W1b  = (bfu*)(ws + 101056512);    //    524,288
  bfu* W2b  = (bfu*)(ws + 101580800);    //    524,288
  float* lossbuf = (float*)(ws + 102105088); // 9,216

  // fp32 -> bf16 staging (single fused launch)
  k_cvt_all<<<6848, 256, 0, stream>>>(m0, m1, m2, Wq, Wk, Wv, W1, W2,
                                      Xb, Wqkv, W1b, W2b);

  k_proj<<<dim3(192, 6), 256, 0, stream>>>(Xb, Wqkv, Qb, Kb, VTb);
  k_attn<<<dim3(16, 16, 9), 256, 0, stream>>>(Qb, Kb, VTb, upd3, lossbuf);
  k_ln1<<<6144, 256, 0, stream>>>(m0, m1, m2, upd3, g1, be1, x1b);
  k_ffn1<<<dim3(192, 8), 256, 0, stream>>>(x1b, W1b, bm1, Hb);
  k_ffn2<<<dim3(192, 4), 256, 0, stream>>>(Hb, W2b, bm2, x1b, x2f);
  k_ln2<<<6144, 256, 0, stream>>>(x2f, g2, be2, out);
  k_loss<<<1, 256, 0, stream>>>(lossbuf, out);
}

// Round 15
// 306.182 us; speedup vs baseline: 1.1454x; 1.1454x over previous
//
#include <hip/hip_runtime.h>

// ---------------------------------------------------------------------------
// UMAALayer: 3-modality cross-attention + pairwise contrastive loss + FFN.
// M=3, B=4, N=2048, D=256, H=4, HD=64, DFF=1024, TEMP=0.07, EPS=1e-5.
// v9 = v7 revert (reg-staged, padded LDS, 0 bank conflicts — gl16/[64][64]
// of v8 aliased banks at 128B row stride, +44us) + v_max3 tree for the loss
// fmax chain. Shift-free softmax P=2^S, max-shifted loss l2run. No atomics.
// ---------------------------------------------------------------------------

typedef float f32x2 __attribute__((ext_vector_type(2)));
typedef float f32x4 __attribute__((ext_vector_type(4)));
typedef float f32x16 __attribute__((ext_vector_type(16)));
typedef __bf16 bf16x8 __attribute__((ext_vector_type(8)));
typedef unsigned int u32x2 __attribute__((ext_vector_type(2)));
typedef unsigned int u32x4 __attribute__((ext_vector_type(4)));
typedef unsigned short bfu4 __attribute__((ext_vector_type(4)));
typedef unsigned short bfu;

#define MFMA32(a, b, c) __builtin_amdgcn_mfma_f32_32x32x16_bf16(a, b, c, 0, 0, 0)

#define NTOK 2048
#define DIMM 256
#define HDIM 64
#define DFF 1024
#define OUT_LOSS 6291456    // 3*4*2048*256
#define INVT 14.285714285714286f   // 1/0.07
#define LN2F 0.6931471805599453f
#define LOG2EF 1.4426950408889634f

#define EXP2F(x) __builtin_amdgcn_exp2f(x)
#define LOG2F(x) __builtin_amdgcn_logf(x)   // v_log_f32 = log2(x)

__device__ __forceinline__ bfu f2bf(float f) {
  unsigned u = __float_as_uint(f);
  u += 0x7FFFu + ((u >> 16) & 1u);          // RNE
  return (bfu)(u >> 16);
}
__device__ __forceinline__ float frombf(bfu v) {
  return __uint_as_float(((unsigned)v) << 16);
}

__device__ __forceinline__ bf16x8 ldfrag(const bfu* p) {
  return __builtin_bit_cast(bf16x8, *reinterpret_cast<const u32x4*>(p));
}

// v_cvt_pk_bf16_f32: D[15:0]=bf16(lo), D[31:16]=bf16(hi)
__device__ __forceinline__ unsigned pkbf(float lo, float hi) {
  unsigned d;
  asm("v_cvt_pk_bf16_f32 %0, %1, %2" : "=v"(d) : "v"(lo), "v"(hi));
  return d;
}
__device__ __forceinline__ void swap32u(unsigned& a, unsigned& b) {
  asm("v_permlane32_swap_b32 %0, %1" : "+v"(a), "+v"(b));
}
__device__ __forceinline__ float red32_add(float x) {
  float y = x;
  asm("v_permlane32_swap_b32 %0, %1" : "+v"(x), "+v"(y));
  return x + y;
}
__device__ __forceinline__ float red32_max(float x) {
  float y = x;
  asm("v_permlane32_swap_b32 %0, %1" : "+v"(x), "+v"(y));
  return fmaxf(x, y);
}

// ---------------- fused fp32 -> bf16 conversion (all 8 tensors) ------------
__global__ __launch_bounds__(256) void k_cvt_all(
    const float* __restrict__ m0, const float* __restrict__ m1,
    const float* __restrict__ m2, const float* __restrict__ Wq,
    const float* __restrict__ Wk, const float* __restrict__ Wv,
    const float* __restrict__ W1, const float* __restrict__ W2,
    bfu* __restrict__ Xb, bfu* __restrict__ Wqkv,
    bfu* __restrict__ W1b, bfu* __restrict__ W2b) {
  const int bid = blockIdx.x, tid = threadIdx.x;
  const float* src;
  bfu* dst;
  int idx;
  if (bid < 6144) {
    const int seg = bid >> 11;
    src = (seg == 0) ? m0 : (seg == 1 ? m1 : m2);
    dst = Xb + (size_t)seg * 2097152;
    idx = (bid & 2047) * 256 + tid;
  } else if (bid < 6336) {
    const int wseg = (bid - 6144) >> 6;
    src = (wseg == 0) ? Wq : (wseg == 1 ? Wk : Wv);
    dst = Wqkv + (size_t)wseg * 65536;
    idx = ((bid - 6144) & 63) * 256 + tid;
  } else if (bid < 6592) {
    src = W1; dst = W1b; idx = (bid - 6336) * 256 + tid;
  } else {
    src = W2; dst = W2b; idx = (bid - 6592) * 256 + tid;
  }
  f32x4 v = reinterpret_cast<const f32x4*>(src)[idx];
  bfu4 o;
  o[0] = f2bf(v[0]); o[1] = f2bf(v[1]); o[2] = f2bf(v[2]); o[3] = f2bf(v[3]);
  reinterpret_cast<bfu4*>(dst)[idx] = o;
}

// ======================= LDS-staged GEMM building blocks ====================
#define RROW(r) (((r) & 3) + 8 * ((r) >> 2) + 4 * hi)

// ---------------- k_proj: [24576,256] x [768,256]^T -> Q/K/VT ---------------
// grid (192, 6). Q pre-scaled by 0.125*log2e (log2-domain scores).
__global__ __launch_bounds__(256) void k_proj(const bfu* __restrict__ Xb,
                                              const bfu* __restrict__ Wcat,
                                              bfu* __restrict__ Qb,
                                              bfu* __restrict__ Kb,
                                              bfu* __restrict__ VTb) {
  __shared__ __align__(16) bfu sA[128][72];
  __shared__ __align__(16) bfu sB[128][72];
  const int tid = threadIdx.x;
  const int lane = tid & 63, w = tid >> 6;
  const int l31 = lane & 31, hi = lane >> 5, hi8 = hi * 8;
  const int wm = w >> 1, wn = w & 1;
  const int row0 = blockIdx.x * 128;
  const int col0 = blockIdx.y * 128;
  const bfu* Ap = Xb + (size_t)row0 * 256;
  const bfu* Bp = Wcat + (size_t)col0 * 256;
  f32x16 acc00 = {}, acc01 = {}, acc10 = {}, acc11 = {};
  u32x4 rA[4], rB[4];
#pragma unroll
  for (int t = 0; t < 4; ++t) {
    const int c = tid + 256 * t;
    rA[t] = *reinterpret_cast<const u32x4*>(Ap + (size_t)(c >> 3) * 256 + (c & 7) * 8);
    rB[t] = *reinterpret_cast<const u32x4*>(Bp + (size_t)(c >> 3) * 256 + (c & 7) * 8);
  }
#pragma unroll
  for (int ks = 0; ks < 4; ++ks) {
    __syncthreads();
#pragma unroll
    for (int t = 0; t < 4; ++t) {
      const int c = tid + 256 * t;
      *reinterpret_cast<u32x4*>(&sA[c >> 3][(c & 7) * 8]) = rA[t];
      *reinterpret_cast<u32x4*>(&sB[c >> 3][(c & 7) * 8]) = rB[t];
    }
    __syncthreads();
    if (ks < 3) {
      const int k0 = (ks + 1) * 64;
#pragma unroll
      for (int t = 0; t < 4; ++t) {
        const int c = tid + 256 * t;
        rA[t] = *reinterpret_cast<const u32x4*>(Ap + (size_t)(c >> 3) * 256 + k0 + (c & 7) * 8);
        rB[t] = *reinterpret_cast<const u32x4*>(Bp + (size_t)(c >> 3) * 256 + k0 + (c & 7) * 8);
      }
    }
#pragma unroll
    for (int kk = 0; kk < 4; ++kk) {
      bf16x8 a0 = ldfrag(&sA[wm * 64 + l31][kk * 16 + hi8]);
      bf16x8 a1 = ldfrag(&sA[wm * 64 + 32 + l31][kk * 16 + hi8]);
      bf16x8 b0 = ldfrag(&sB[wn * 64 + l31][kk * 16 + hi8]);
      bf16x8 b1 = ldfrag(&sB[wn * 64 + 32 + l31][kk * 16 + hi8]);
      acc00 = MFMA32(a0, b0, acc00);
      acc01 = MFMA32(a0, b1, acc01);
      acc10 = MFMA32(a1, b0, acc10);
      acc11 = MFMA32(a1, b1, acc11);
    }
  }
  const int mb = row0 >> 11;                    // (m*4+b), uniform per block
  const int cb = col0 + wn * 64;                // 64-aligned -> which,h uniform
  const int which = cb >> 8;
  const int h = (cb >> 6) & 3;
  const size_t obase = ((size_t)mb * 4 + h) * ((size_t)NTOK * HDIM);
  const int tokb = (row0 & 2047) + wm * 64;
  const float qs = (which == 0) ? 0.125f * LOG2EF : 1.0f;
#define STORE_QK(ACC, MT, NT)                                                 \
  {                                                                           \
    bfu* dst = (which ? Kb : Qb) + obase;                                     \
    _Pragma("unroll") for (int r = 0; r < 16; ++r) {                          \
      const int tok = tokb + (MT) * 32 + RROW(r);                             \
      dst[(size_t)tok * 64 + (NT) * 32 + l31] = f2bf((ACC)[r] * qs);          \
    }                                                                         \
  }
#define STORE_VT(ACC, MT, NT)                                                 \
  {                                                                           \
    _Pragma("unroll") for (int g = 0; g < 4; ++g) {                           \
      bfu4 pk;                                                                \
      _Pragma("unroll") for (int q = 0; q < 4; ++q) pk[q] = f2bf((ACC)[4 * g + q]); \
      const int tok = tokb + (MT) * 32 + 8 * g + 4 * hi;                      \
      *reinterpret_cast<bfu4*>(                                               \
          &VTb[obase + (size_t)((NT) * 32 + l31) * NTOK + tok]) = pk;         \
    }                                                                         \
  }
  if (which < 2) {
    STORE_QK(acc00, 0, 0) STORE_QK(acc01, 0, 1)
    STORE_QK(acc10, 1, 0) STORE_QK(acc11, 1, 1)
  } else {
    STORE_VT(acc00, 0, 0) STORE_VT(acc01, 0, 1)
    STORE_VT(acc10, 1, 0) STORE_VT(acc11, 1, 1)
  }
}

// ---------------- k_ffn1: h = gelu(x1b @ W1^T + bm1) ------------------------
__global__ __launch_bounds__(256) void k_ffn1(const bfu* __restrict__ x1b,
                                              const bfu* __restrict__ W1b,
                                              const float* __restrict__ bm1,
                                              bfu* __restrict__ hb) {
  __shared__ __align__(16) bfu sA[128][72];
  __shared__ __align__(16) bfu sB[128][72];
  const int tid = threadIdx.x;
  const int lane = tid & 63, w = tid >> 6;
  const int l31 = lane & 31, hi = lane >> 5, hi8 = hi * 8;
  const int wm = w >> 1, wn = w & 1;
  const int row0 = blockIdx.x * 128;
  const int col0 = blockIdx.y * 128;
  const bfu* Ap = x1b + (size_t)row0 * 256;
  const bfu* Bp = W1b + (size_t)col0 * 256;
  f32x16 acc00 = {}, acc01 = {}, acc10 = {}, acc11 = {};
  u32x4 rA[4], rB[4];
#pragma unroll
  for (int t = 0; t < 4; ++t) {
    const int c = tid + 256 * t;
    rA[t] = *reinterpret_cast<const u32x4*>(Ap + (size_t)(c >> 3) * 256 + (c & 7) * 8);
    rB[t] = *reinterpret_cast<const u32x4*>(Bp + (size_t)(c >> 3) * 256 + (c & 7) * 8);
  }
#pragma unroll
  for (int ks = 0; ks < 4; ++ks) {
    __syncthreads();
#pragma unroll
    for (int t = 0; t < 4; ++t) {
      const int c = tid + 256 * t;
      *reinterpret_cast<u32x4*>(&sA[c >> 3][(c & 7) * 8]) = rA[t];
      *reinterpret_cast<u32x4*>(&sB[c >> 3][(c & 7) * 8]) = rB[t];
    }
    __syncthreads();
    if (ks < 3) {
      const int k0 = (ks + 1) * 64;
#pragma unroll
      for (int t = 0; t < 4; ++t) {
        const int c = tid + 256 * t;
        rA[t] = *reinterpret_cast<const u32x4*>(Ap + (size_t)(c >> 3) * 256 + k0 + (c & 7) * 8);
        rB[t] = *reinterpret_cast<const u32x4*>(Bp + (size_t)(c >> 3) * 256 + k0 + (c & 7) * 8);
      }
    }
#pragma unroll
    for (int kk = 0; kk < 4; ++kk) {
      bf16x8 a0 = ldfrag(&sA[wm * 64 + l31][kk * 16 + hi8]);
      bf16x8 a1 = ldfrag(&sA[wm * 64 + 32 + l31][kk * 16 + hi8]);
      bf16x8 b0 = ldfrag(&sB[wn * 64 + l31][kk * 16 + hi8]);
      bf16x8 b1 = ldfrag(&sB[wn * 64 + 32 + l31][kk * 16 + hi8]);
      acc00 = MFMA32(a0, b0, acc00);
      acc01 = MFMA32(a0, b1, acc01);
      acc10 = MFMA32(a1, b0, acc10);
      acc11 = MFMA32(a1, b1, acc11);
    }
  }
  const int tokb = row0 + wm * 64;
#define STORE_H(ACC, MT, NT)                                                  \
  {                                                                           \
    const int e = col0 + wn * 64 + (NT) * 32 + l31;                           \
    const float bias = bm1[e];                                                \
    _Pragma("unroll") for (int r = 0; r < 16; ++r) {                          \
      const int tok = tokb + (MT) * 32 + RROW(r);                             \
      float v = (ACC)[r] + bias;                                              \
      v = 0.5f * v * (1.0f + erff(v * 0.70710678118f));                       \
      hb[(size_t)tok * DFF + e] = f2bf(v);                                    \
    }                                                                         \
  }
  STORE_H(acc00, 0, 0) STORE_H(acc01, 0, 1)
  STORE_H(acc10, 1, 0) STORE_H(acc11, 1, 1)
}

// ---------------- k_ffn2: y = hb @ W2^T + bm2 + x1 (pre-LN) -> x2f ----------
__global__ __launch_bounds__(256) void k_ffn2(const bfu* __restrict__ hb,
                                              const bfu* __restrict__ W2b,
                                              const float* __restrict__ bm2,
                                              const bfu* __restrict__ x1b,
                                              float* __restrict__ x2f) {
  __shared__ __align__(16) bfu sA[128][72];
  __shared__ __align__(16) bfu sB[64][72];
  const int tid = threadIdx.x;
  const int lane = tid & 63, w = tid >> 6;
  const int l31 = lane & 31, hi = lane >> 5, hi8 = hi * 8;
  const int row0 = blockIdx.x * 128;
  const int col0 = blockIdx.y * 64;
  const bfu* Ap = hb + (size_t)row0 * DFF;
  const bfu* Bp = W2b + (size_t)col0 * DFF;
  f32x16 acc0 = {}, acc1 = {};
  u32x4 rA[4], rB[2];
#pragma unroll
  for (int t = 0; t < 4; ++t) {
    const int c = tid + 256 * t;
    rA[t] = *reinterpret_cast<const u32x4*>(Ap + (size_t)(c >> 3) * DFF + (c & 7) * 8);
  }
#pragma unroll
  for (int t = 0; t < 2; ++t) {
    const int c = tid + 256 * t;
    rB[t] = *reinterpret_cast<const u32x4*>(Bp + (size_t)(c >> 3) * DFF + (c & 7) * 8);
  }
  for (int ks = 0; ks < 16; ++ks) {
    __syncthreads();
#pragma unroll
    for (int t = 0; t < 4; ++t) {
      const int c = tid + 256 * t;
      *reinterpret_cast<u32x4*>(&sA[c >> 3][(c & 7) * 8]) = rA[t];
    }
#pragma unroll
    for (int t = 0; t < 2; ++t) {
      const int c = tid + 256 * t;
      *reinterpret_cast<u32x4*>(&sB[c >> 3][(c & 7) * 8]) = rB[t];
    }
    __syncthreads();
    if (ks < 15) {
      const int k0 = (ks + 1) * 64;
#pragma unroll
      for (int t = 0; t < 4; ++t) {
        const int c = tid + 256 * t;
        rA[t] = *reinterpret_cast<const u32x4*>(Ap + (size_t)(c >> 3) * DFF + k0 + (c & 7) * 8);
      }
#pragma unroll
      for (int t = 0; t < 2; ++t) {
        const int c = tid + 256 * t;
        rB[t] = *reinterpret_cast<const u32x4*>(Bp + (size_t)(c >> 3) * DFF + k0 + (c & 7) * 8);
      }
    }
#pragma unroll
    for (int kk = 0; kk < 4; ++kk) {
      bf16x8 a = ldfrag(&sA[w * 32 + l31][kk * 16 + hi8]);
      bf16x8 b0 = ldfrag(&sB[l31][kk * 16 + hi8]);
      bf16x8 b1 = ldfrag(&sB[32 + l31][kk * 16 + hi8]);
      acc0 = MFMA32(a, b0, acc0);
      acc1 = MFMA32(a, b1, acc1);
    }
  }
  const int tokb = row0 + w * 32;
#define STORE_Y(ACC, NT)                                                      \
  {                                                                           \
    const int e = col0 + (NT) * 32 + l31;                                     \
    const float bias = bm2[e];                                                \
    _Pragma("unroll") for (int r = 0; r < 16; ++r) {                          \
      const int tok = tokb + RROW(r);                                         \
      x2f[(size_t)tok * DIMM + e] =                                           \
          (ACC)[r] + bias + frombf(x1b[(size_t)tok * DIMM + e]);              \
    }                                                                         \
  }
  STORE_Y(acc0, 0) STORE_Y(acc1, 1)
}

// ---------------- fused cross-attention + contrastive-loss v9 --------------
// grid (16 qt, 16 bh, 9 ij): one (i,j) pair per block; i==j blocks skip loss.
// 4 waves x 32 q-rows; double-buffer padded LDS, ONE barrier per K-tile.
// Softmax shift-free (P=2^S, O unscaled); max tracking only feeds the loss
// l2run (defer THR=1.9), skipped when i==j; pmax via v_max3 tree.
__global__ __launch_bounds__(256, 3) void k_attn(const bfu* __restrict__ Qb,
                                                 const bfu* __restrict__ Kb,
                                                 const bfu* __restrict__ VTb,
                                                 bfu* __restrict__ upd3,
                                                 float* __restrict__ lossbuf) {
  __shared__ __align__(16) bfu sK[2][64][72];
  __shared__ __align__(16) bfu sV[2][64][72];
  __shared__ float sRed[4];
  const int tid = threadIdx.x;
  const int lane = tid & 63, w = tid >> 6;
  const int l31 = lane & 31, hi = lane >> 5;
  const int hi8 = hi * 8;
  const int qt = blockIdx.x, bh = blockIdx.y, ij = blockIdx.z;
  const int i = ij / 3, j = ij % 3;
  const bool wl = (i != j);
  const int b = bh >> 2, h = bh & 3;
  const int q0 = qt * 128 + w * 32;
  const int q = q0 + l31;
  const int ktd = q0 >> 6;                 // kt index containing the diagonal
  const size_t plane = (size_t)NTOK * HDIM;
  const size_t qoff = (((size_t)i * 4 + b) * 4 + h) * plane;
  const size_t kvoff = (((size_t)j * 4 + b) * 4 + h) * plane;
  const bfu* Kp = Kb + kvoff;
  const bfu* Vp = VTb + kvoff;
  const int r0 = tid >> 2, c0 = (tid & 3) * 2;

  bf16x8 qf[4];
#pragma unroll
  for (int c = 0; c < 4; ++c)
    qf[c] = ldfrag(Qb + qoff + (size_t)q * HDIM + c * 16 + hi8);

  float lossacc = 0.0f;
  float mrun = -1e30f, lrun = 0.0f, l2run = 0.0f;
  f32x16 O0 = {}, O1 = {};
  u32x4 pk0, pk1, pv0, pv1;

#define ISSUE_TILE(K0)                                                       \
    {                                                                        \
      const bfu* kp_ = Kp + (size_t)((K0) + r0) * HDIM + c0 * 8;             \
      pk0 = *reinterpret_cast<const u32x4*>(kp_);                            \
      pk1 = *reinterpret_cast<const u32x4*>(kp_ + 8);                        \
      const bfu* vp_ = Vp + (size_t)r0 * NTOK + (K0) + c0 * 8;               \
      pv0 = *reinterpret_cast<const u32x4*>(vp_);                            \
      pv1 = *reinterpret_cast<const u32x4*>(vp_ + 8);                        \
    }
#define WRITE_TILE(BUF)                                                      \
    {                                                                        \
      *reinterpret_cast<u32x4*>(&sK[BUF][r0][c0 * 8]) = pk0;                 \
      *reinterpret_cast<u32x4*>(&sK[BUF][r0][c0 * 8 + 8]) = pk1;             \
      *reinterpret_cast<u32x4*>(&sV[BUF][r0][c0 * 8]) = pv0;                 \
      *reinterpret_cast<u32x4*>(&sV[BUF][r0][c0 * 8 + 8]) = pv1;             \
    }

  ISSUE_TILE(0);
  WRITE_TILE(0);
  __syncthreads();
  int cur = 0;

  for (int kt = 0; kt < 32; ++kt) {
    if (kt < 31) ISSUE_TILE((kt + 1) * 64);   // issue-early prefetch

    // ---- S^T = K_tile x Q  (64k x 32q per wave), log2-domain ----
    f32x16 S0 = {}, S1 = {};
    __builtin_amdgcn_s_setprio(1);
#pragma unroll
    for (int c = 0; c < 4; ++c) {
      bf16x8 a0 = ldfrag(&sK[cur][l31][c * 16 + hi8]);
      bf16x8 a1 = ldfrag(&sK[cur][32 + l31][c * 16 + hi8]);
      S0 = MFMA32(a0, qf[c], S0);
      S1 = MFMA32(a1, qf[c], S1);
    }
    __builtin_amdgcn_s_setprio(0);

    if (wl) {
      // ---- loss diagonal: sim = S * ln2 ----
      if (kt == ktd) {
#pragma unroll
        for (int r = 0; r < 16; ++r) {
          const int klow = (r & 3) + 8 * (r >> 2) + 4 * hi;
          const float sv = (w & 1) ? S1[r] : S0[r];
          if (klow == l31) lossacc -= sv * LN2F;
        }
      }
      // ---- loss max tracking (defer, THR=1.9) — v_max3 tree ----
      float pa = S0[0], pb = S1[0];
#pragma unroll
      for (int r = 1; r < 15; r += 2) {
        pa = fmaxf(fmaxf(pa, S0[r]), S0[r + 1]);   // fuses to v_max3
        pb = fmaxf(fmaxf(pb, S1[r]), S1[r + 1]);
      }
      float pmax = fmaxf(fmaxf(pa, S0[15]), fmaxf(pb, S1[15]));
      pmax = red32_max(pmax);
      if (__any(pmax > mrun + 1.9f)) {
        const float mnew = fmaxf(mrun, pmax);
        l2run *= EXP2F((mrun - mnew) * INVT);
        mrun = mnew;
      }
    }

    // ---- softmax exps (shift-free) + loss exps (max-shifted) ----
    const float mI = mrun * INVT;
    f32x2 psv = {};
    f32x2 p2v = {};
#pragma unroll
    for (int r = 0; r < 16; ++r) {
      const float e0 = EXP2F(S0[r]), e1 = EXP2F(S1[r]);
      f32x2 ev; ev[0] = e0; ev[1] = e1;
      psv += ev;
      if (wl) {
        f32x2 pv2;
        pv2[0] = EXP2F(fmaf(S0[r], INVT, -mI));
        pv2[1] = EXP2F(fmaf(S1[r], INVT, -mI));
        p2v += pv2;
      }
      S0[r] = e0; S1[r] = e1;
    }
    lrun += red32_add(psv[0] + psv[1]);
    if (wl) l2run += red32_add(p2v[0] + p2v[1]);

    // ---- per-chunk: build P^T B-fragment in-register, then its PV MFMAs ----
    __builtin_amdgcn_s_setprio(1);
#pragma unroll
    for (int c = 0; c < 4; ++c) {
      const int half = c >> 1, sub = c & 1;
      unsigned q01, q23, q45, q67;
      if (half == 0) {
        q01 = pkbf(S0[sub * 8 + 0], S0[sub * 8 + 1]);
        q23 = pkbf(S0[sub * 8 + 2], S0[sub * 8 + 3]);
        q45 = pkbf(S0[sub * 8 + 4], S0[sub * 8 + 5]);
        q67 = pkbf(S0[sub * 8 + 6], S0[sub * 8 + 7]);
      } else {
        q01 = pkbf(S1[sub * 8 + 0], S1[sub * 8 + 1]);
        q23 = pkbf(S1[sub * 8 + 2], S1[sub * 8 + 3]);
        q45 = pkbf(S1[sub * 8 + 4], S1[sub * 8 + 5]);
        q67 = pkbf(S1[sub * 8 + 6], S1[sub * 8 + 7]);
      }
      swap32u(q01, q45);
      swap32u(q23, q67);
      u32x4 bb; bb[0] = q01; bb[1] = q23; bb[2] = q45; bb[3] = q67;
      const bf16x8 pb2 = __builtin_bit_cast(bf16x8, bb);
      bf16x8 a0 = ldfrag(&sV[cur][l31][c * 16 + hi8]);
      bf16x8 a1 = ldfrag(&sV[cur][32 + l31][c * 16 + hi8]);
      O0 = MFMA32(a0, pb2, O0);
      O1 = MFMA32(a1, pb2, O1);
    }
    __builtin_amdgcn_s_setprio(0);

    // write next tile into the OTHER buffer (its readers finished before the
    // previous barrier), then one barrier publishes it + retires buf[cur].
    if (kt < 31) WRITE_TILE(cur ^ 1);
    __syncthreads();
    cur ^= 1;
  }  // kt

  // ---- store O/l (bf16) to this block's exclusive upd3 slice ----
  const float inv = 1.0f / lrun;
  bfu* up = upd3 + ((size_t)((j * 3 + i) * 4 + b) * NTOK + q) * DIMM + h * 64;
#pragma unroll
  for (int g = 0; g < 4; ++g) {
    u32x2 st0, st1;
    st0[0] = pkbf(O0[4 * g + 0] * inv, O0[4 * g + 1] * inv);
    st0[1] = pkbf(O0[4 * g + 2] * inv, O0[4 * g + 3] * inv);
    st1[0] = pkbf(O1[4 * g + 0] * inv, O1[4 * g + 1] * inv);
    st1[1] = pkbf(O1[4 * g + 2] * inv, O1[4 * g + 3] * inv);
    *reinterpret_cast<u32x2*>(up + 8 * g + 4 * hi) = st0;
    *reinterpret_cast<u32x2*>(up + 32 + 8 * g + 4 * hi) = st1;
  }
  // lse contribution: ln2 * (m*INVT + log2(l2run))
  if (wl && hi == 0)
    lossacc += LN2F * (mrun * INVT + LOG2F(l2run));

  float v = lossacc;
#pragma unroll
  for (int mk = 1; mk < 64; mk <<= 1) v += __shfl_xor(v, mk);
  if (lane == 0) sRed[w] = v;
  __syncthreads();
  if (tid == 0)
    lossbuf[((size_t)ij * 16 + bh) * 16 + qt] =
        sRed[0] + sRed[1] + sRed[2] + sRed[3];
}

// ---------------- residual + LayerNorm1 (1 row / wave) ---------------------
__global__ __launch_bounds__(256) void k_ln1(const float* __restrict__ m0,
                                             const float* __restrict__ m1,
                                             const float* __restrict__ m2,
                                             const bfu* __restrict__ upd3,
                                             const float* __restrict__ g1,
                                             const float* __restrict__ be1,
                                             bfu* __restrict__ x1b) {
  const int tid = threadIdx.x;
  const int lane = tid & 63, w = tid >> 6;
  const int row = blockIdx.x * 4 + w;
  const int i = row >> 13;
  const int rr = row & 8191;
  const float* src = (i == 0 ? m0 : (i == 1 ? m1 : m2)) + (size_t)rr * DIMM;
  f32x4 x = *reinterpret_cast<const f32x4*>(src + lane * 4);
#pragma unroll
  for (int j = 0; j < 3; ++j) {
    bfu4 uv = *reinterpret_cast<const bfu4*>(
        upd3 + ((size_t)(j * 3 + i) * 8192 + rr) * DIMM + lane * 4);
#pragma unroll
    for (int qi = 0; qi < 4; ++qi) x[qi] += frombf(uv[qi]);
  }
  float s = x[0] + x[1] + x[2] + x[3];
  float s2 = x[0] * x[0] + x[1] * x[1] + x[2] * x[2] + x[3] * x[3];
#pragma unroll
  for (int mk = 1; mk < 64; mk <<= 1) { s += __shfl_xor(s, mk); s2 += __shfl_xor(s2, mk); }
  const float mu = s * (1.0f / 256.0f);
  const float var = s2 * (1.0f / 256.0f) - mu * mu;
  const float rstd = rsqrtf(var + 1e-5f);
  f32x4 g = *reinterpret_cast<const f32x4*>(g1 + lane * 4);
  f32x4 bb = *reinterpret_cast<const f32x4*>(be1 + lane * 4);
  bfu4 ob;
#pragma unroll
  for (int qi = 0; qi < 4; ++qi)
    ob[qi] = f2bf((x[qi] - mu) * rstd * g[qi] + bb[qi]);
  *reinterpret_cast<bfu4*>(x1b + (size_t)row * DIMM + lane * 4) = ob;
}

// ---------------- LayerNorm2: x2f -> out ------------------------------------
__global__ __launch_bounds__(256) void k_ln2(const float* __restrict__ x2f,
                                             const float* __restrict__ g2,
                                             const float* __restrict__ be2,
                                             float* __restrict__ out) {
  const int tid = threadIdx.x;
  const int lane = tid & 63, w = tid >> 6;
  const int row = blockIdx.x * 4 + w;
  f32x4 x = *reinterpret_cast<const f32x4*>(x2f + (size_t)row * DIMM + lane * 4);
  float s = x[0] + x[1] + x[2] + x[3];
  float s2 = x[0] * x[0] + x[1] * x[1] + x[2] * x[2] + x[3] * x[3];
#pragma unroll
  for (int mk = 1; mk < 64; mk <<= 1) { s += __shfl_xor(s, mk); s2 += __shfl_xor(s2, mk); }
  const float mu = s * (1.0f / 256.0f);
  const float var = s2 * (1.0f / 256.0f) - mu * mu;
  const float rstd = rsqrtf(var + 1e-5f);
  f32x4 g = *reinterpret_cast<const f32x4*>(g2 + lane * 4);
  f32x4 bb = *reinterpret_cast<const f32x4*>(be2 + lane * 4);
  f32x4 o;
#pragma unroll
  for (int qi = 0; qi < 4; ++qi) o[qi] = (x[qi] - mu) * rstd * g[qi] + bb[qi];
  *reinterpret_cast<f32x4*>(out + (size_t)row * DIMM + lane * 4) = o;
}

// ---------------- final loss reduce (deterministic) -------------------------
__global__ __launch_bounds__(256) void k_loss(const float* __restrict__ lossbuf,
                                              float* __restrict__ out) {
  __shared__ float red[4];
  const int tid = threadIdx.x;
  float s = 0.0f;
  for (int idx = tid; idx < 2304; idx += 256) s += lossbuf[idx];
#pragma unroll
  for (int mk = 1; mk < 64; mk <<= 1) s += __shfl_xor(s, mk);
  if ((tid & 63) == 0) red[tid >> 6] = s;
  __syncthreads();
  if (tid == 0)
    out[OUT_LOSS] = (red[0] + red[1] + red[2] + red[3]) * (1.0f / (32768.0f * 2.0f));
}

// ---------------------------------------------------------------------------
extern "C" void kernel_launch(void* const* d_in, const int* in_sizes, int n_in,
                              void* d_out, int out_size, void* d_ws, size_t ws_size,
                              hipStream_t stream) {
  const float* m0 = (const float*)d_in[0];
  const float* m1 = (const float*)d_in[1];
  const float* m2 = (const float*)d_in[2];
  const float* Wq = (const float*)d_in[3];
  const float* Wk = (const float*)d_in[4];
  const float* Wv = (const float*)d_in[5];
  const float* g1 = (const float*)d_in[6];
  const float* be1 = (const float*)d_in[7];
  const float* W1 = (const float*)d_in[8];
  const float* bm1 = (const float*)d_in[9];
  const float* W2 = (const float*)d_in[10];
  const float* bm2 = (const float*)d_in[11];
  const float* g2 = (const float*)d_in[12];
  const float* be2 = (const float*)d_in[13];
  float* out = (float*)d_out;

  // workspace layout (bytes), peak ~102.2 MB (same as v7)
  char* ws = (char*)d_ws;
  bfu* Xb   = (bfu*)(ws + 0);            // 12,582,912
  bfu* Wqkv = (bfu*)(ws + 12582912);     //    393,216
  bfu* Qb   = (bfu*)(ws + 12976128);     // 12,582,912
  bfu* Kb   = (bfu*)(ws + 25559040);     // 12,582,912
  bfu* VTb  = (bfu*)(ws + 38141952);     // 12,582,912
  bfu* Hb   = (bfu*)(ws + 0);            // 50,331,648 [overlay]
  bfu* upd3 = (bfu*)(ws + 50724864);     // 37,748,736 (3 slices bf16)
  float* x2f = (float*)(ws + 50724864);  // 25,165,824 [overlays upd3 after ln1]
  bfu* x1b  = (bfu*)(ws + 88473600);     // 12,582,912
  bfu* W1b  = (bfu*)(ws + 101056512);    //    524,288
  bfu* W2b  = (bfu*)(ws + 101580800);    //    524,288
  float* lossbuf = (float*)(ws + 102105088); // 9,216

  // fp32 -> bf16 staging (single fused launch)
  k_cvt_all<<<6848, 256, 0, stream>>>(m0, m1, m2, Wq, Wk, Wv, W1, W2,
                                      Xb, Wqkv, W1b, W2b);

  k_proj<<<dim3(192, 6), 256, 0, stream>>>(Xb, Wqkv, Qb, Kb, VTb);
  k_attn<<<dim3(16, 16, 9), 256, 0, stream>>>(Qb, Kb, VTb, upd3, lossbuf);
  k_ln1<<<6144, 256, 0, stream>>>(m0, m1, m2, upd3, g1, be1, x1b);
  k_ffn1<<<dim3(192, 8), 256, 0, stream>>>(x1b, W1b, bm1, Hb);
  k_ffn2<<<dim3(192, 4), 256, 0, stream>>>(Hb, W2b, bm2, x1b, x2f);
  k_ln2<<<6144, 256, 0, stream>>>(x2f, g2, be2, out);
  k_loss<<<1, 256, 0, stream>>>(lossbuf, out);
}